// Round 1
// baseline (67.147 us; speedup 1.0000x reference)
//
#include <hip/hip_runtime.h>
#include <math.h>

// PeriodicGeometryAdapter: per (b,n,m) pair, min over 27 periodic images of
// the Gram-metric squared distance; outputs concatenated flat:
//   [0]                 pair_delta_min (B,N,N,3)
//   [3*S]               pair_dist      (B,N,N)      S = B*N*N
//   [4*S]               pair_dist2     (B,N,N)
//   [5*S]               pair_dist_norm (B,N,N)
//   [6*S]               pair_mask      (B,N,N)  (bool -> 1.0f/0.0f)
//   [7*S]               lattice_y1     (B,6)
//   [7*S+6B]            gram           (B,3,3)
//   [7*S+6B+9B]         cell_scale     (B,1)

__global__ __launch_bounds__(256) void pga_kernel(
    const float* __restrict__ coords,          // (B,N,3)
    const unsigned char* __restrict__ pad_mask,// (B,N) bool
    const float* __restrict__ lattice,         // (B,6)
    float* __restrict__ out,
    int B, int N)
{
    const int bid = blockIdx.x;
    const int b = bid / N;
    const int n = bid - b * N;
    const int m = threadIdx.x;              // blockDim.x == N
    if (m >= N) return;

    // ---- per-batch lattice -> gram, cell_scale (redundant per thread, cheap) ----
    const float l0 = lattice[b*6+0], l1 = lattice[b*6+1], l2 = lattice[b*6+2];
    const float l3 = lattice[b*6+3], l4 = lattice[b*6+4], l5 = lattice[b*6+5];
    const float la = expf(l0), lb = expf(l1), lc = expf(l2);
    const float ca = tanhf(l3), cb = tanhf(l4), cg = tanhf(l5);
    const float G00 = la*la;
    const float G01 = la*lb*cg;   // == G10 exactly (same arithmetic as ref)
    const float G02 = la*lc*cb;
    const float G11 = lb*lb;
    const float G12 = lb*lc*ca;
    const float G22 = lc*lc;
    const float cell_scale = fmaxf((la + lb + lc) * (1.0f/3.0f), 1e-8f);

    // ---- pair delta ----
    const float xn = coords[((size_t)b*N + n)*3 + 0];
    const float yn = coords[((size_t)b*N + n)*3 + 1];
    const float zn = coords[((size_t)b*N + n)*3 + 2];
    const float xm = coords[((size_t)b*N + m)*3 + 0];
    const float ym = coords[((size_t)b*N + m)*3 + 1];
    const float zm = coords[((size_t)b*N + m)*3 + 2];
    const float dx = xn - xm, dy = yn - ym, dz = zn - zm;

    // ---- 27-image argmin (lexicographic offset order = itertools.product) ----
    float best_d2 = INFINITY;
    float bx = 0.f, by = 0.f, bz = 0.f;
    #pragma unroll
    for (int ox = -1; ox <= 1; ++ox) {
        #pragma unroll
        for (int oy = -1; oy <= 1; ++oy) {
            #pragma unroll
            for (int oz = -1; oz <= 1; ++oz) {
                const float ix = dx + (float)ox;
                const float iy = dy + (float)oy;
                const float iz = dz + (float)oz;
                // einsum structure: tmp_j = sum_i img_i * G_ij ; d2 = sum_j tmp_j * img_j
                const float t0 = (ix*G00 + iy*G01) + iz*G02;
                const float t1 = (ix*G01 + iy*G11) + iz*G12;
                const float t2 = (ix*G02 + iy*G12) + iz*G22;
                const float d2 = (t0*ix + t1*iy) + t2*iz;
                if (d2 < best_d2) {   // strict < keeps FIRST min, matches argmin
                    best_d2 = d2; bx = ix; by = iy; bz = iz;
                }
            }
        }
    }

    const bool valid_n = (pad_mask[(size_t)b*N + n] == 0);
    const bool valid_m = (pad_mask[(size_t)b*N + m] == 0);
    const bool pm = valid_n && valid_m;

    float d2c  = fmaxf(best_d2, 0.0f);
    float dist = sqrtf(d2c);
    float dnrm = dist / cell_scale;
    if (!pm) { bx = by = bz = 0.f; dist = 0.f; d2c = 0.f; dnrm = 0.f; }

    const size_t S = (size_t)B * N * N;
    const size_t p = ((size_t)b * N + n) * N + m;

    out[3*p + 0] = bx;
    out[3*p + 1] = by;
    out[3*p + 2] = bz;
    out[3*S + p] = dist;
    out[4*S + p] = d2c;
    out[5*S + p] = dnrm;
    out[6*S + p] = pm ? 1.0f : 0.0f;

    // ---- per-batch outputs, written once per batch (block n==0) ----
    if (n == 0) {
        float* lat_o  = out + 7*S;                    // (B,6)
        float* gram_o = lat_o + (size_t)B*6;          // (B,9)
        float* cs_o   = gram_o + (size_t)B*9;         // (B,)
        if (m < 6) lat_o[(size_t)b*6 + m] = lattice[b*6 + m];
        if (m == 0) {
            gram_o[(size_t)b*9 + 0] = G00;
            gram_o[(size_t)b*9 + 1] = G01;
            gram_o[(size_t)b*9 + 2] = G02;
            gram_o[(size_t)b*9 + 3] = G01;
            gram_o[(size_t)b*9 + 4] = G11;
            gram_o[(size_t)b*9 + 5] = G12;
            gram_o[(size_t)b*9 + 6] = G02;
            gram_o[(size_t)b*9 + 7] = G12;
            gram_o[(size_t)b*9 + 8] = G22;
            cs_o[b] = cell_scale;
        }
    }
}

extern "C" void kernel_launch(void* const* d_in, const int* in_sizes, int n_in,
                              void* d_out, int out_size, void* d_ws, size_t ws_size,
                              hipStream_t stream) {
    const float*         coords   = (const float*)d_in[0];
    const unsigned char* pad_mask = (const unsigned char*)d_in[1];
    const float*         lattice  = (const float*)d_in[2];
    float* out = (float*)d_out;

    const int B = in_sizes[2] / 6;          // lattice (B,6)
    const int N = in_sizes[1] / B;          // pad_mask (B,N)

    dim3 grid(B * N);
    dim3 block(N);
    pga_kernel<<<grid, block, 0, stream>>>(coords, pad_mask, lattice, out, B, N);
}